// Round 2
// baseline (312.499 us; speedup 1.0000x reference)
//
#include <hip/hip_runtime.h>
#include <math.h>

#define F_   256
#define FEAT_EMB_ 63
#define HID_ 128
#define OUT_ 7

// ---------------------------------------------------------------------------
// 1. Column statistics of x [N, 256]: per-column sum and sum-of-squares.
//    Wave-per-row float4 loads (fully coalesced, 4 rows per block-iter),
//    LDS cross-wave reduce, 8 atomics per column-group per block.
// ---------------------------------------------------------------------------
__global__ __launch_bounds__(256) void colstats_kernel(const float* __restrict__ x,
                                                       float* __restrict__ colsum,
                                                       float* __restrict__ colsq,
                                                       int n) {
    __shared__ float4 ssum[4][64];
    __shared__ float4 ssq[4][64];
    int t = threadIdx.x;
    int rl = t >> 6;        // wave = row-lane 0..3
    int cg = t & 63;        // float4 column group
    float4 s = make_float4(0.f, 0.f, 0.f, 0.f);
    float4 q = make_float4(0.f, 0.f, 0.f, 0.f);
    for (int r = blockIdx.x * 4 + rl; r < n; r += gridDim.x * 4) {
        float4 v = *(const float4*)(x + (size_t)r * F_ + cg * 4);
        s.x += v.x; s.y += v.y; s.z += v.z; s.w += v.w;
        q.x += v.x * v.x; q.y += v.y * v.y; q.z += v.z * v.z; q.w += v.w * v.w;
    }
    ssum[rl][cg] = s;
    ssq[rl][cg] = q;
    __syncthreads();
    if (rl == 0) {
#pragma unroll
        for (int i = 1; i < 4; i++) {
            float4 a = ssum[i][cg], b = ssq[i][cg];
            s.x += a.x; s.y += a.y; s.z += a.z; s.w += a.w;
            q.x += b.x; q.y += b.y; q.z += b.z; q.w += b.w;
        }
        atomicAdd(&colsum[cg * 4 + 0], s.x);
        atomicAdd(&colsum[cg * 4 + 1], s.y);
        atomicAdd(&colsum[cg * 4 + 2], s.z);
        atomicAdd(&colsum[cg * 4 + 3], s.w);
        atomicAdd(&colsq[cg * 4 + 0], q.x);
        atomicAdd(&colsq[cg * 4 + 1], q.y);
        atomicAdd(&colsq[cg * 4 + 2], q.z);
        atomicAdd(&colsq[cg * 4 + 3], q.w);
    }
}

// ---------------------------------------------------------------------------
// 2. Finalize mean / reciprocal-std
// ---------------------------------------------------------------------------
__global__ void stats_finalize_kernel(const float* __restrict__ colsum,
                                      const float* __restrict__ colsq,
                                      float* __restrict__ mean,
                                      float* __restrict__ rstd, int n) {
    int t = threadIdx.x;
    float m = colsum[t] / (float)n;
    float var = colsq[t] / (float)n - m * m;
    var = fmaxf(var, 0.f);
    float sd = sqrtf(var);
    mean[t] = m;
    rstd[t] = (sd == 0.f) ? 1.f : (1.f / sd);
}

// ---------------------------------------------------------------------------
// 3. In-degree histogram over edges (dst side)
// ---------------------------------------------------------------------------
__global__ void deg_kernel(const int* __restrict__ ei, int* __restrict__ deg, int E) {
    int e = blockIdx.x * 256 + threadIdx.x;
    if (e < E) atomicAdd(&deg[ei[E + e]], 1);
}

// ---------------------------------------------------------------------------
// 4. Exclusive scan of deg -> offsets[N+1]; fused dinv = rsqrt(deg+1)
// ---------------------------------------------------------------------------
__global__ __launch_bounds__(1024) void scan_kernel(const int* __restrict__ deg,
                                                    int* __restrict__ offsets,
                                                    float* __restrict__ dinv, int n) {
    __shared__ int part[1024];
    int t = threadIdx.x;
    int ch = (n + 1023) / 1024;
    int lo = t * ch, hi = min(lo + ch, n);
    int s = 0;
    for (int i = lo; i < hi; i++) {
        int dg = deg[i];
        s += dg;
        dinv[i] = rsqrtf((float)dg + 1.0f);
    }
    part[t] = s;
    __syncthreads();
    for (int off = 1; off < 1024; off <<= 1) {
        int v = (t >= off) ? part[t - off] : 0;
        __syncthreads();
        part[t] += v;
        __syncthreads();
    }
    int run = part[t] - s;   // exclusive prefix for this chunk
    if (t == 0) offsets[0] = 0;
    for (int i = lo; i < hi; i++) {
        run += deg[i];
        offsets[i + 1] = run;
    }
}

// ---------------------------------------------------------------------------
// 5. Scatter edges into CSR adjacency (grouped by dst, order arbitrary)
// ---------------------------------------------------------------------------
__global__ void scatter_kernel(const int* __restrict__ ei, const int* __restrict__ offsets,
                               int* __restrict__ cursor, int* __restrict__ adj, int E) {
    int e = blockIdx.x * 256 + threadIdx.x;
    if (e < E) {
        int s = ei[e];
        int d = ei[E + e];
        int pos = offsets[d] + atomicAdd(&cursor[d], 1);
        adj[pos] = s;
    }
}

// ---------------------------------------------------------------------------
// 6. Cp[k] += sum_{f, j<63} emb[f,j] * W1[f*64+j, k]   (node-independent part)
//    one block per f; thread (jg, k4); 8 float4 loads per thread; LDS reduce.
// ---------------------------------------------------------------------------
__global__ __launch_bounds__(256) void cvec_kernel(const float* __restrict__ emb,
                                                   const float* __restrict__ W1,
                                                   float* __restrict__ Cp) {
    __shared__ float4 red[8][32];
    int f = blockIdx.x;
    int t = threadIdx.x;
    int jg = t >> 5;        // 0..7
    int k4 = t & 31;        // float4 col group
    float4 s = make_float4(0.f, 0.f, 0.f, 0.f);
    for (int j = jg; j < FEAT_EMB_; j += 8) {
        float e = emb[f * FEAT_EMB_ + j];
        float4 w = *(const float4*)(W1 + ((size_t)(f * 64 + j)) * HID_ + k4 * 4);
        s.x += e * w.x; s.y += e * w.y; s.z += e * w.z; s.w += e * w.w;
    }
    red[jg][k4] = s;
    __syncthreads();
    if (jg == 0) {
#pragma unroll
        for (int i = 1; i < 8; i++) {
            float4 a = red[i][k4];
            s.x += a.x; s.y += a.y; s.z += a.z; s.w += a.w;
        }
        atomicAdd(&Cp[k4 * 4 + 0], s.x);
        atomicAdd(&Cp[k4 * 4 + 1], s.y);
        atomicAdd(&Cp[k4 * 4 + 2], s.z);
        atomicAdd(&Cp[k4 * 4 + 3], s.w);
    }
}

// ---------------------------------------------------------------------------
// 7. Wv[f,k] = rstd[f] * W1[f*64+63, k]  (compact 128 KB, L2-resident for mm1)
//    Cp[k]  -= mean[f] * Wv[f,k]         (folds normalization shift)
// ---------------------------------------------------------------------------
__global__ __launch_bounds__(128) void wprep_kernel(const float* __restrict__ W1,
                                                    const float* __restrict__ mean,
                                                    const float* __restrict__ rstd,
                                                    float* __restrict__ Wv,
                                                    float* __restrict__ Cp) {
    int f = blockIdx.x;
    int k = threadIdx.x;
    float w = W1[((size_t)(f * 64 + 63)) * HID_ + k] * rstd[f];
    Wv[f * HID_ + k] = w;
    atomicAdd(&Cp[k], -mean[f] * w);
}

// ---------------------------------------------------------------------------
// 8. g0 = (Cp + x @ Wv) * dinv   (normalization already folded into Wv/Cp)
//    Tiled fp32 GEMM: 32-row tile, full 128 cols, K=256 in 64-chunks.
// ---------------------------------------------------------------------------
__global__ __launch_bounds__(256) void mm1_kernel(const float* __restrict__ x,
                                                  const float* __restrict__ Wv,
                                                  const float* __restrict__ Cp,
                                                  const float* __restrict__ dinv,
                                                  float* __restrict__ g0, int n) {
    __shared__ float xs[32][64];     // 8 KB
    __shared__ float wt[64][128];    // 32 KB
    int t = threadIdx.x;
    int tx = t & 31;                 // cols tx*4 .. tx*4+3
    int ty = t >> 5;                 // rows ty*4 .. ty*4+3
    int rowBase = blockIdx.x * 32;

    float acc[4][4] = {};

    for (int kb = 0; kb < 256; kb += 64) {
#pragma unroll
        for (int i = 0; i < 2; i++) {
            int idx = t + i * 256;
            int r = idx >> 4;
            int c4 = (idx & 15) * 4;
            int gr = rowBase + r;
            float4 v = make_float4(0.f, 0.f, 0.f, 0.f);
            if (gr < n) v = *(const float4*)(x + (size_t)gr * F_ + kb + c4);
            *(float4*)(&xs[r][c4]) = v;
        }
#pragma unroll
        for (int i = 0; i < 8; i++) {
            int idx = t + i * 256;
            int kr = idx >> 5;
            int c4 = (idx & 31) * 4;
            float4 v = *(const float4*)(Wv + (size_t)(kb + kr) * HID_ + c4);
            *(float4*)(&wt[kr][c4]) = v;
        }
        __syncthreads();

#pragma unroll 4
        for (int k = 0; k < 64; k += 4) {
            float4 wv0 = *(const float4*)(&wt[k + 0][tx * 4]);
            float4 wv1 = *(const float4*)(&wt[k + 1][tx * 4]);
            float4 wv2 = *(const float4*)(&wt[k + 2][tx * 4]);
            float4 wv3 = *(const float4*)(&wt[k + 3][tx * 4]);
#pragma unroll
            for (int i = 0; i < 4; i++) {
                float4 xv = *(const float4*)(&xs[ty * 4 + i][k]);
                acc[i][0] += xv.x * wv0.x; acc[i][1] += xv.x * wv0.y;
                acc[i][2] += xv.x * wv0.z; acc[i][3] += xv.x * wv0.w;
                acc[i][0] += xv.y * wv1.x; acc[i][1] += xv.y * wv1.y;
                acc[i][2] += xv.y * wv1.z; acc[i][3] += xv.y * wv1.w;
                acc[i][0] += xv.z * wv2.x; acc[i][1] += xv.z * wv2.y;
                acc[i][2] += xv.z * wv2.z; acc[i][3] += xv.z * wv2.w;
                acc[i][0] += xv.w * wv3.x; acc[i][1] += xv.w * wv3.y;
                acc[i][2] += xv.w * wv3.z; acc[i][3] += xv.w * wv3.w;
            }
        }
        __syncthreads();
    }

    int cb = tx * 4;
    float4 cv = *(const float4*)(Cp + cb);
#pragma unroll
    for (int i = 0; i < 4; i++) {
        int gr = rowBase + ty * 4 + i;
        if (gr < n) {
            float dv = dinv[gr];
            float4 o;
            o.x = (acc[i][0] + cv.x) * dv;
            o.y = (acc[i][1] + cv.y) * dv;
            o.z = (acc[i][2] + cv.z) * dv;
            o.w = (acc[i][3] + cv.w) * dv;
            *(float4*)(g0 + (size_t)gr * HID_ + cb) = o;
        }
    }
}

// ---------------------------------------------------------------------------
// 9. Layer-1 aggregation + ReLU + fused FC2.
//    One wave per node, lane holds 2 channels. Batched coalesced load of up
//    to 64 adj indices, __shfl broadcast, unroll-4 independent gathers.
// ---------------------------------------------------------------------------
__global__ __launch_bounds__(256) void agg_fc2_kernel(const float* __restrict__ g0,
                                                      const int* __restrict__ offsets,
                                                      const int* __restrict__ adj,
                                                      const float* __restrict__ dinv,
                                                      const float* __restrict__ b1,
                                                      const float* __restrict__ W2,
                                                      float* __restrict__ g2, int n) {
    int wave = threadIdx.x >> 6;
    int lane = threadIdx.x & 63;
    int d = blockIdx.x * 4 + wave;
    if (d >= n) return;

    int o0 = offsets[d];
    int o1 = offsets[d + 1];
    float2 acc = *(const float2*)(g0 + (size_t)d * HID_ + lane * 2);  // self loop

    for (int base = o0; base < o1; base += 64) {
        int idx = (base + lane < o1) ? adj[base + lane] : 0;
        int cnt = min(64, o1 - base);
        int j = 0;
        for (; j + 4 <= cnt; j += 4) {
            int s0 = __shfl(idx, j + 0);
            int s1 = __shfl(idx, j + 1);
            int s2 = __shfl(idx, j + 2);
            int s3 = __shfl(idx, j + 3);
            float2 v0 = *(const float2*)(g0 + (size_t)s0 * HID_ + lane * 2);
            float2 v1 = *(const float2*)(g0 + (size_t)s1 * HID_ + lane * 2);
            float2 v2 = *(const float2*)(g0 + (size_t)s2 * HID_ + lane * 2);
            float2 v3 = *(const float2*)(g0 + (size_t)s3 * HID_ + lane * 2);
            acc.x += v0.x + v1.x + v2.x + v3.x;
            acc.y += v0.y + v1.y + v2.y + v3.y;
        }
        for (; j < cnt; j++) {
            int s = __shfl(idx, j);
            float2 v = *(const float2*)(g0 + (size_t)s * HID_ + lane * 2);
            acc.x += v.x;
            acc.y += v.y;
        }
    }

    float dv = dinv[d];
    float2 bb = *(const float2*)(b1 + lane * 2);
    float h0 = fmaxf(acc.x * dv + bb.x, 0.f);
    float h1 = fmaxf(acc.y * dv + bb.y, 0.f);

    const float* w2a = W2 + (lane * 2) * OUT_;
    const float* w2b = W2 + (lane * 2 + 1) * OUT_;
    float r[OUT_];
#pragma unroll
    for (int c = 0; c < OUT_; c++) {
        float p = h0 * w2a[c] + h1 * w2b[c];
#pragma unroll
        for (int off = 32; off > 0; off >>= 1) p += __shfl_xor(p, off);
        r[c] = p;
    }
    if (lane < 8) {
        float val;
        switch (lane) {
            case 0: val = r[0]; break;
            case 1: val = r[1]; break;
            case 2: val = r[2]; break;
            case 3: val = r[3]; break;
            case 4: val = r[4]; break;
            case 5: val = r[5]; break;
            case 6: val = r[6]; break;
            default: val = 0.f; break;   // pad slot
        }
        g2[(size_t)d * 8 + lane] = val * dv;
    }
}

// ---------------------------------------------------------------------------
// 10. Layer-2 aggregation + bias + log_softmax. 8 lanes per node.
// ---------------------------------------------------------------------------
__global__ __launch_bounds__(256) void agg2_softmax_kernel(const float* __restrict__ g2,
                                                           const int* __restrict__ offsets,
                                                           const int* __restrict__ adj,
                                                           const float* __restrict__ dinv,
                                                           const float* __restrict__ b2,
                                                           float* __restrict__ out, int n) {
    int t = threadIdx.x;
    int g = t >> 3;
    int c = t & 7;
    int d = blockIdx.x * 32 + g;
    if (d >= n) return;

    int o0 = offsets[d];
    int o1 = offsets[d + 1];
    float acc = g2[(size_t)d * 8 + c];       // self loop (pad slot holds 0)
    for (int i = o0; i < o1; i++) {
        int s = adj[i];
        acc += g2[(size_t)s * 8 + c];
    }
    float z = (c < OUT_) ? (acc * dinv[d] + b2[c]) : -INFINITY;
    float m = z;
#pragma unroll
    for (int off = 4; off > 0; off >>= 1) m = fmaxf(m, __shfl_xor(m, off, 8));
    float e = (c < OUT_) ? __expf(z - m) : 0.f;
    float sum = e;
#pragma unroll
    for (int off = 4; off > 0; off >>= 1) sum += __shfl_xor(sum, off, 8);
    if (c < OUT_) out[(size_t)d * OUT_ + c] = z - m - __logf(sum);
}

// ---------------------------------------------------------------------------
// launch
// ---------------------------------------------------------------------------
extern "C" void kernel_launch(void* const* d_in, const int* in_sizes, int n_in,
                              void* d_out, int out_size, void* d_ws, size_t ws_size,
                              hipStream_t stream) {
    const float* x    = (const float*)d_in[0];
    const float* emb  = (const float*)d_in[1];
    const float* W1   = (const float*)d_in[2];
    const float* b1   = (const float*)d_in[3];
    const float* W2   = (const float*)d_in[4];
    const float* b2   = (const float*)d_in[5];
    const int*   ei   = (const int*)d_in[6];
    float* out = (float*)d_out;

    const int N = in_sizes[0] / F_;       // 20000
    const int E = in_sizes[6] / 2;        // 320000

    // workspace layout (element offsets, all 4-byte elems)
    float* ws = (float*)d_ws;
    size_t o = 0;
    float* colsum  = ws + o; o += F_;          // zeroed
    float* colsq   = ws + o; o += F_;          // zeroed
    float* Cp      = ws + o; o += HID_;        // zeroed (atomic target)
    size_t zero1_elems = o;                    // 640 floats
    float* mean    = ws + o; o += F_;
    float* rstd    = ws + o; o += F_;
    float* Wv      = ws + o; o += (size_t)F_ * HID_;   // compact 128 KB
    float* dinv    = ws + o; o += N;
    int*   deg     = (int*)(ws + o); o += N;
    int*   cursor  = (int*)(ws + o); o += N;   // contiguous with deg -> one memset
    int*   offsets = (int*)(ws + o); o += (size_t)N + 1;
    o = (o + 3) & ~(size_t)3;
    int*   adj     = (int*)(ws + o); o += E;
    o = (o + 3) & ~(size_t)3;
    float* g0      = ws + o; o += (size_t)N * HID_;
    float* g2      = ws + o; o += (size_t)N * 8;

    hipMemsetAsync(ws, 0, zero1_elems * sizeof(float), stream);
    hipMemsetAsync(deg, 0, (size_t)2 * N * sizeof(int), stream);

    colstats_kernel<<<512, 256, 0, stream>>>(x, colsum, colsq, N);
    deg_kernel<<<(E + 255) / 256, 256, 0, stream>>>(ei, deg, E);
    stats_finalize_kernel<<<1, 256, 0, stream>>>(colsum, colsq, mean, rstd, N);
    cvec_kernel<<<F_, 256, 0, stream>>>(emb, W1, Cp);
    scan_kernel<<<1, 1024, 0, stream>>>(deg, offsets, dinv, N);
    scatter_kernel<<<(E + 255) / 256, 256, 0, stream>>>(ei, offsets, cursor, adj, E);
    wprep_kernel<<<F_, 128, 0, stream>>>(W1, mean, rstd, Wv, Cp);
    mm1_kernel<<<(N + 31) / 32, 256, 0, stream>>>(x, Wv, Cp, dinv, g0, N);
    agg_fc2_kernel<<<(N + 3) / 4, 256, 0, stream>>>(g0, offsets, adj, dinv, b1, W2, g2, N);
    agg2_softmax_kernel<<<(N + 31) / 32, 256, 0, stream>>>(g2, offsets, adj, dinv, b2, out, N);
}

// Round 3
// 309.293 us; speedup vs baseline: 1.0104x; 1.0104x over previous
//
#include <hip/hip_runtime.h>
#include <math.h>

#define F_   256
#define FEAT_EMB_ 63
#define HID_ 128
#define OUT_ 7

// ---------------------------------------------------------------------------
// 1. Column statistics of x [N, 256]: per-column sum and sum-of-squares.
//    625 blocks; each wave owns 8 consecutive rows with 8 UNROLLED independent
//    float4 loads per lane (latency hiding via MLP, not grid-stride looping).
//    R2 lesson: 262 GB/s was outstanding-load-bound, not coalescing-bound.
// ---------------------------------------------------------------------------
__global__ __launch_bounds__(256) void colstats_kernel(const float* __restrict__ x,
                                                       float* __restrict__ colsum,
                                                       float* __restrict__ colsq,
                                                       int n) {
    __shared__ float4 ssum[4][64];
    __shared__ float4 ssq[4][64];
    int t = threadIdx.x;
    int rl = t >> 6;        // wave 0..3
    int lane = t & 63;      // float4 column group
    int row0 = blockIdx.x * 32 + rl * 8;

    float4 v[8];
#pragma unroll
    for (int i = 0; i < 8; i++) {
        int r = row0 + i;
        v[i] = (r < n) ? *(const float4*)(x + (size_t)r * F_ + lane * 4)
                       : make_float4(0.f, 0.f, 0.f, 0.f);
    }
    float4 s = make_float4(0.f, 0.f, 0.f, 0.f);
    float4 q = make_float4(0.f, 0.f, 0.f, 0.f);
#pragma unroll
    for (int i = 0; i < 8; i++) {
        s.x += v[i].x; s.y += v[i].y; s.z += v[i].z; s.w += v[i].w;
        q.x += v[i].x * v[i].x; q.y += v[i].y * v[i].y;
        q.z += v[i].z * v[i].z; q.w += v[i].w * v[i].w;
    }
    ssum[rl][lane] = s;
    ssq[rl][lane] = q;
    __syncthreads();
    if (rl == 0) {
#pragma unroll
        for (int i = 1; i < 4; i++) {
            float4 a = ssum[i][lane], b = ssq[i][lane];
            s.x += a.x; s.y += a.y; s.z += a.z; s.w += a.w;
            q.x += b.x; q.y += b.y; q.z += b.z; q.w += b.w;
        }
        atomicAdd(&colsum[lane * 4 + 0], s.x);
        atomicAdd(&colsum[lane * 4 + 1], s.y);
        atomicAdd(&colsum[lane * 4 + 2], s.z);
        atomicAdd(&colsum[lane * 4 + 3], s.w);
        atomicAdd(&colsq[lane * 4 + 0], q.x);
        atomicAdd(&colsq[lane * 4 + 1], q.y);
        atomicAdd(&colsq[lane * 4 + 2], q.z);
        atomicAdd(&colsq[lane * 4 + 3], q.w);
    }
}

// ---------------------------------------------------------------------------
// 2. In-degree histogram over edges (dst side)
// ---------------------------------------------------------------------------
__global__ void deg_kernel(const int* __restrict__ ei, int* __restrict__ deg, int E) {
    int e = blockIdx.x * 256 + threadIdx.x;
    if (e < E) atomicAdd(&deg[ei[E + e]], 1);
}

// ---------------------------------------------------------------------------
// 3. Exclusive scan of deg -> offsets[N+1]; fused dinv = rsqrt(deg+1)
// ---------------------------------------------------------------------------
__global__ __launch_bounds__(1024) void scan_kernel(const int* __restrict__ deg,
                                                    int* __restrict__ offsets,
                                                    float* __restrict__ dinv, int n) {
    __shared__ int part[1024];
    int t = threadIdx.x;
    int ch = (n + 1023) / 1024;
    int lo = t * ch, hi = min(lo + ch, n);
    int s = 0;
    for (int i = lo; i < hi; i++) {
        int dg = deg[i];
        s += dg;
        dinv[i] = rsqrtf((float)dg + 1.0f);
    }
    part[t] = s;
    __syncthreads();
    for (int off = 1; off < 1024; off <<= 1) {
        int v = (t >= off) ? part[t - off] : 0;
        __syncthreads();
        part[t] += v;
        __syncthreads();
    }
    int run = part[t] - s;   // exclusive prefix for this chunk
    if (t == 0) offsets[0] = 0;
    for (int i = lo; i < hi; i++) {
        run += deg[i];
        offsets[i + 1] = run;
    }
}

// ---------------------------------------------------------------------------
// 4. Scatter edges into CSR adjacency (grouped by dst, order arbitrary)
// ---------------------------------------------------------------------------
__global__ void scatter_kernel(const int* __restrict__ ei, const int* __restrict__ offsets,
                               int* __restrict__ cursor, int* __restrict__ adj, int E) {
    int e = blockIdx.x * 256 + threadIdx.x;
    if (e < E) {
        int s = ei[e];
        int d = ei[E + e];
        int pos = offsets[d] + atomicAdd(&cursor[d], 1);
        adj[pos] = s;
    }
}

// ---------------------------------------------------------------------------
// 5. Cp[k] += sum_{f, j<63} emb[f,j] * W1[f*64+j, k]   (node-independent part)
// ---------------------------------------------------------------------------
__global__ __launch_bounds__(256) void cvec_kernel(const float* __restrict__ emb,
                                                   const float* __restrict__ W1,
                                                   float* __restrict__ Cp) {
    __shared__ float4 red[8][32];
    int f = blockIdx.x;
    int t = threadIdx.x;
    int jg = t >> 5;        // 0..7
    int k4 = t & 31;        // float4 col group
    float4 s = make_float4(0.f, 0.f, 0.f, 0.f);
    for (int j = jg; j < FEAT_EMB_; j += 8) {
        float e = emb[f * FEAT_EMB_ + j];
        float4 w = *(const float4*)(W1 + ((size_t)(f * 64 + j)) * HID_ + k4 * 4);
        s.x += e * w.x; s.y += e * w.y; s.z += e * w.z; s.w += e * w.w;
    }
    red[jg][k4] = s;
    __syncthreads();
    if (jg == 0) {
#pragma unroll
        for (int i = 1; i < 8; i++) {
            float4 a = red[i][k4];
            s.x += a.x; s.y += a.y; s.z += a.z; s.w += a.w;
        }
        atomicAdd(&Cp[k4 * 4 + 0], s.x);
        atomicAdd(&Cp[k4 * 4 + 1], s.y);
        atomicAdd(&Cp[k4 * 4 + 2], s.z);
        atomicAdd(&Cp[k4 * 4 + 3], s.w);
    }
}

// ---------------------------------------------------------------------------
// 6. Wv[f,k] = rstd[f] * W1[f*64+63, k]; Cp[k] -= mean[f]*Wv[f,k]
//    mean/rstd recomputed inline from colsum/colsq (stats_finalize fused away).
// ---------------------------------------------------------------------------
__global__ __launch_bounds__(128) void wprep_kernel(const float* __restrict__ W1,
                                                    const float* __restrict__ colsum,
                                                    const float* __restrict__ colsq,
                                                    float* __restrict__ Wv,
                                                    float* __restrict__ Cp, int n) {
    int f = blockIdx.x;
    int k = threadIdx.x;
    float m = colsum[f] / (float)n;
    float var = fmaxf(colsq[f] / (float)n - m * m, 0.f);
    float sd = sqrtf(var);
    float rstd = (sd == 0.f) ? 1.f : (1.f / sd);
    float w = W1[((size_t)(f * 64 + 63)) * HID_ + k] * rstd;
    Wv[f * HID_ + k] = w;
    atomicAdd(&Cp[k], -m * w);
}

// ---------------------------------------------------------------------------
// 7. g0 = (Cp + x @ Wv) * dinv.  BK=32: LDS 20 KB -> 8 blocks/CU ceiling.
//    (R2's 40 KB tile profiled with a 30 ms outlier dispatch; de-risked.)
// ---------------------------------------------------------------------------
__global__ __launch_bounds__(256) void mm1_kernel(const float* __restrict__ x,
                                                  const float* __restrict__ Wv,
                                                  const float* __restrict__ Cp,
                                                  const float* __restrict__ dinv,
                                                  float* __restrict__ g0, int n) {
    __shared__ float xs[32][32];     // 4 KB
    __shared__ float wt[32][128];    // 16 KB
    int t = threadIdx.x;
    int tx = t & 31;                 // cols tx*4 .. tx*4+3
    int ty = t >> 5;                 // rows ty*4 .. ty*4+3
    int rowBase = blockIdx.x * 32;

    float acc[4][4] = {};

    for (int kb = 0; kb < 256; kb += 32) {
        {   // stage xs: 32 rows x 32 k = 256 float4, one per thread
            int r = t >> 3;
            int c4 = (t & 7) * 4;
            int gr = rowBase + r;
            float4 v = make_float4(0.f, 0.f, 0.f, 0.f);
            if (gr < n) v = *(const float4*)(x + (size_t)gr * F_ + kb + c4);
            *(float4*)(&xs[r][c4]) = v;
        }
#pragma unroll
        for (int i = 0; i < 4; i++) {   // stage wt: 32 k x 128 cols
            int idx = t + i * 256;
            int kr = idx >> 5;
            int c4 = (idx & 31) * 4;
            *(float4*)(&wt[kr][c4]) = *(const float4*)(Wv + (size_t)(kb + kr) * HID_ + c4);
        }
        __syncthreads();

#pragma unroll
        for (int k = 0; k < 32; k += 4) {
            float4 wv0 = *(const float4*)(&wt[k + 0][tx * 4]);
            float4 wv1 = *(const float4*)(&wt[k + 1][tx * 4]);
            float4 wv2 = *(const float4*)(&wt[k + 2][tx * 4]);
            float4 wv3 = *(const float4*)(&wt[k + 3][tx * 4]);
#pragma unroll
            for (int i = 0; i < 4; i++) {
                float4 xv = *(const float4*)(&xs[ty * 4 + i][k]);
                acc[i][0] += xv.x * wv0.x; acc[i][1] += xv.x * wv0.y;
                acc[i][2] += xv.x * wv0.z; acc[i][3] += xv.x * wv0.w;
                acc[i][0] += xv.y * wv1.x; acc[i][1] += xv.y * wv1.y;
                acc[i][2] += xv.y * wv1.z; acc[i][3] += xv.y * wv1.w;
                acc[i][0] += xv.z * wv2.x; acc[i][1] += xv.z * wv2.y;
                acc[i][2] += xv.z * wv2.z; acc[i][3] += xv.z * wv2.w;
                acc[i][0] += xv.w * wv3.x; acc[i][1] += xv.w * wv3.y;
                acc[i][2] += xv.w * wv3.z; acc[i][3] += xv.w * wv3.w;
            }
        }
        __syncthreads();
    }

    int cb = tx * 4;
    float4 cv = *(const float4*)(Cp + cb);
#pragma unroll
    for (int i = 0; i < 4; i++) {
        int gr = rowBase + ty * 4 + i;
        if (gr < n) {
            float dv = dinv[gr];
            float4 o;
            o.x = (acc[i][0] + cv.x) * dv;
            o.y = (acc[i][1] + cv.y) * dv;
            o.z = (acc[i][2] + cv.z) * dv;
            o.w = (acc[i][3] + cv.w) * dv;
            *(float4*)(g0 + (size_t)gr * HID_ + cb) = o;
        }
    }
}

// ---------------------------------------------------------------------------
// 8. Layer-1 aggregation + ReLU + fused FC2.
// ---------------------------------------------------------------------------
__global__ __launch_bounds__(256) void agg_fc2_kernel(const float* __restrict__ g0,
                                                      const int* __restrict__ offsets,
                                                      const int* __restrict__ adj,
                                                      const float* __restrict__ dinv,
                                                      const float* __restrict__ b1,
                                                      const float* __restrict__ W2,
                                                      float* __restrict__ g2, int n) {
    int wave = threadIdx.x >> 6;
    int lane = threadIdx.x & 63;
    int d = blockIdx.x * 4 + wave;
    if (d >= n) return;

    int o0 = offsets[d];
    int o1 = offsets[d + 1];
    float2 acc = *(const float2*)(g0 + (size_t)d * HID_ + lane * 2);  // self loop

    for (int base = o0; base < o1; base += 64) {
        int idx = (base + lane < o1) ? adj[base + lane] : 0;
        int cnt = min(64, o1 - base);
        int j = 0;
        for (; j + 4 <= cnt; j += 4) {
            int s0 = __shfl(idx, j + 0);
            int s1 = __shfl(idx, j + 1);
            int s2 = __shfl(idx, j + 2);
            int s3 = __shfl(idx, j + 3);
            float2 v0 = *(const float2*)(g0 + (size_t)s0 * HID_ + lane * 2);
            float2 v1 = *(const float2*)(g0 + (size_t)s1 * HID_ + lane * 2);
            float2 v2 = *(const float2*)(g0 + (size_t)s2 * HID_ + lane * 2);
            float2 v3 = *(const float2*)(g0 + (size_t)s3 * HID_ + lane * 2);
            acc.x += v0.x + v1.x + v2.x + v3.x;
            acc.y += v0.y + v1.y + v2.y + v3.y;
        }
        for (; j < cnt; j++) {
            int s = __shfl(idx, j);
            float2 v = *(const float2*)(g0 + (size_t)s * HID_ + lane * 2);
            acc.x += v.x;
            acc.y += v.y;
        }
    }

    float dv = dinv[d];
    float2 bb = *(const float2*)(b1 + lane * 2);
    float h0 = fmaxf(acc.x * dv + bb.x, 0.f);
    float h1 = fmaxf(acc.y * dv + bb.y, 0.f);

    const float* w2a = W2 + (lane * 2) * OUT_;
    const float* w2b = W2 + (lane * 2 + 1) * OUT_;
    float r[OUT_];
#pragma unroll
    for (int c = 0; c < OUT_; c++) {
        float p = h0 * w2a[c] + h1 * w2b[c];
#pragma unroll
        for (int off = 32; off > 0; off >>= 1) p += __shfl_xor(p, off);
        r[c] = p;
    }
    if (lane < 8) {
        float val;
        switch (lane) {
            case 0: val = r[0]; break;
            case 1: val = r[1]; break;
            case 2: val = r[2]; break;
            case 3: val = r[3]; break;
            case 4: val = r[4]; break;
            case 5: val = r[5]; break;
            case 6: val = r[6]; break;
            default: val = 0.f; break;   // pad slot
        }
        g2[(size_t)d * 8 + lane] = val * dv;
    }
}

// ---------------------------------------------------------------------------
// 9. Layer-2 aggregation + bias + log_softmax. 8 lanes per node.
// ---------------------------------------------------------------------------
__global__ __launch_bounds__(256) void agg2_softmax_kernel(const float* __restrict__ g2,
                                                           const int* __restrict__ offsets,
                                                           const int* __restrict__ adj,
                                                           const float* __restrict__ dinv,
                                                           const float* __restrict__ b2,
                                                           float* __restrict__ out, int n) {
    int t = threadIdx.x;
    int g = t >> 3;
    int c = t & 7;
    int d = blockIdx.x * 32 + g;
    if (d >= n) return;

    int o0 = offsets[d];
    int o1 = offsets[d + 1];
    float acc = g2[(size_t)d * 8 + c];       // self loop (pad slot holds 0)
    int i = o0;
    for (; i + 2 <= o1; i += 2) {            // two independent gather chains
        int s0 = adj[i], s1 = adj[i + 1];
        acc += g2[(size_t)s0 * 8 + c] + g2[(size_t)s1 * 8 + c];
    }
    for (; i < o1; i++) acc += g2[(size_t)adj[i] * 8 + c];

    float z = (c < OUT_) ? (acc * dinv[d] + b2[c]) : -INFINITY;
    float m = z;
#pragma unroll
    for (int off = 4; off > 0; off >>= 1) m = fmaxf(m, __shfl_xor(m, off, 8));
    float e = (c < OUT_) ? __expf(z - m) : 0.f;
    float sum = e;
#pragma unroll
    for (int off = 4; off > 0; off >>= 1) sum += __shfl_xor(sum, off, 8);
    if (c < OUT_) out[(size_t)d * OUT_ + c] = z - m - __logf(sum);
}

// ---------------------------------------------------------------------------
// launch
// ---------------------------------------------------------------------------
extern "C" void kernel_launch(void* const* d_in, const int* in_sizes, int n_in,
                              void* d_out, int out_size, void* d_ws, size_t ws_size,
                              hipStream_t stream) {
    const float* x    = (const float*)d_in[0];
    const float* emb  = (const float*)d_in[1];
    const float* W1   = (const float*)d_in[2];
    const float* b1   = (const float*)d_in[3];
    const float* W2   = (const float*)d_in[4];
    const float* b2   = (const float*)d_in[5];
    const int*   ei   = (const int*)d_in[6];
    float* out = (float*)d_out;

    const int N = in_sizes[0] / F_;       // 20000
    const int E = in_sizes[6] / 2;        // 320000

    float* ws = (float*)d_ws;
    size_t o = 0;
    float* colsum  = ws + o; o += F_;          // zeroed
    float* colsq   = ws + o; o += F_;          // zeroed
    float* Cp      = ws + o; o += HID_;        // zeroed (atomic target)
    size_t zero1_elems = o;                    // 640 floats
    float* Wv      = ws + o; o += (size_t)F_ * HID_;   // compact 128 KB
    float* dinv    = ws + o; o += N;
    int*   deg     = (int*)(ws + o); o += N;
    int*   cursor  = (int*)(ws + o); o += N;   // contiguous with deg -> one memset
    int*   offsets = (int*)(ws + o); o += (size_t)N + 1;
    o = (o + 3) & ~(size_t)3;
    int*   adj     = (int*)(ws + o); o += E;
    o = (o + 3) & ~(size_t)3;
    float* g0      = ws + o; o += (size_t)N * HID_;
    float* g2      = ws + o; o += (size_t)N * 8;

    hipMemsetAsync(ws, 0, zero1_elems * sizeof(float), stream);
    hipMemsetAsync(deg, 0, (size_t)2 * N * sizeof(int), stream);

    colstats_kernel<<<(N + 31) / 32, 256, 0, stream>>>(x, colsum, colsq, N);
    deg_kernel<<<(E + 255) / 256, 256, 0, stream>>>(ei, deg, E);
    cvec_kernel<<<F_, 256, 0, stream>>>(emb, W1, Cp);
    scan_kernel<<<1, 1024, 0, stream>>>(deg, offsets, dinv, N);
    scatter_kernel<<<(E + 255) / 256, 256, 0, stream>>>(ei, offsets, cursor, adj, E);
    wprep_kernel<<<F_, 128, 0, stream>>>(W1, colsum, colsq, Wv, Cp, N);
    mm1_kernel<<<(N + 31) / 32, 256, 0, stream>>>(x, Wv, Cp, dinv, g0, N);
    agg_fc2_kernel<<<(N + 3) / 4, 256, 0, stream>>>(g0, offsets, adj, dinv, b1, W2, g2, N);
    agg2_softmax_kernel<<<(N + 31) / 32, 256, 0, stream>>>(g2, offsets, adj, dinv, b2, out, N);
}

// Round 4
// 225.545 us; speedup vs baseline: 1.3855x; 1.3713x over previous
//
#include <hip/hip_runtime.h>
#include <math.h>

#define F_   256
#define FEAT_EMB_ 63
#define HID_ 128
#define OUT_ 7

typedef short short8 __attribute__((ext_vector_type(8)));
typedef float f32x4 __attribute__((ext_vector_type(4)));

__device__ inline short f2bf(float f) {
    unsigned u = __float_as_uint(f);
    u += 0x7FFFu + ((u >> 16) & 1u);     // round-to-nearest-even
    return (short)(u >> 16);
}

// ---------------------------------------------------------------------------
// 1. Column stats of x [N,256]. R3 lesson: time scaled with #blocks doing
//    same-address atomics (~50ns each serialized), NOT with load pattern.
//    Fix: 8-way partial buffers (blockIdx&7) -> 78 adds/address, overlapped.
//    N = 20000 = 625*32 exactly -> no bounds checks.
// ---------------------------------------------------------------------------
__global__ __launch_bounds__(256) void colstats_kernel(const float* __restrict__ x,
                                                       float* __restrict__ colsum8,
                                                       float* __restrict__ colsq8) {
    __shared__ float4 ssum[4][64];
    __shared__ float4 ssq[4][64];
    int t = threadIdx.x;
    int rl = t >> 6;
    int lane = t & 63;
    int row0 = blockIdx.x * 32 + rl * 8;

    float4 v[8];
#pragma unroll
    for (int i = 0; i < 8; i++)
        v[i] = *(const float4*)(x + (size_t)(row0 + i) * F_ + lane * 4);

    float4 s = make_float4(0.f, 0.f, 0.f, 0.f);
    float4 q = make_float4(0.f, 0.f, 0.f, 0.f);
#pragma unroll
    for (int i = 0; i < 8; i++) {
        s.x += v[i].x; s.y += v[i].y; s.z += v[i].z; s.w += v[i].w;
        q.x += v[i].x * v[i].x; q.y += v[i].y * v[i].y;
        q.z += v[i].z * v[i].z; q.w += v[i].w * v[i].w;
    }
    ssum[rl][lane] = s;
    ssq[rl][lane] = q;
    __syncthreads();
    if (rl == 0) {
#pragma unroll
        for (int i = 1; i < 4; i++) {
            float4 a = ssum[i][lane], b = ssq[i][lane];
            s.x += a.x; s.y += a.y; s.z += a.z; s.w += a.w;
            q.x += b.x; q.y += b.y; q.z += b.z; q.w += b.w;
        }
        int buf = (blockIdx.x & 7) * F_;
        atomicAdd(&colsum8[buf + lane * 4 + 0], s.x);
        atomicAdd(&colsum8[buf + lane * 4 + 1], s.y);
        atomicAdd(&colsum8[buf + lane * 4 + 2], s.z);
        atomicAdd(&colsum8[buf + lane * 4 + 3], s.w);
        atomicAdd(&colsq8[buf + lane * 4 + 0], q.x);
        atomicAdd(&colsq8[buf + lane * 4 + 1], q.y);
        atomicAdd(&colsq8[buf + lane * 4 + 2], q.z);
        atomicAdd(&colsq8[buf + lane * 4 + 3], q.w);
    }
}

// ---------------------------------------------------------------------------
// 2. Finalize mean / rstd from the 8 partial buffers (1 block, 256 threads)
// ---------------------------------------------------------------------------
__global__ void stats_kernel(const float* __restrict__ colsum8,
                             const float* __restrict__ colsq8,
                             float* __restrict__ mean,
                             float* __restrict__ rstd, int n) {
    int f = threadIdx.x;
    float s = 0.f, q = 0.f;
#pragma unroll
    for (int b = 0; b < 8; b++) {
        s += colsum8[b * F_ + f];
        q += colsq8[b * F_ + f];
    }
    float m = s / (float)n;
    float var = fmaxf(q / (float)n - m * m, 0.f);
    float sd = sqrtf(var);
    mean[f] = m;
    rstd[f] = (sd == 0.f) ? 1.f : (1.f / sd);
}

// ---------------------------------------------------------------------------
// 3. In-degree histogram (dst side)
// ---------------------------------------------------------------------------
__global__ void deg_kernel(const int* __restrict__ ei, int* __restrict__ deg, int E) {
    int e = blockIdx.x * 256 + threadIdx.x;
    if (e < E) atomicAdd(&deg[ei[E + e]], 1);
}

// ---------------------------------------------------------------------------
// 4. Exclusive scan of deg -> offsets[N+1]; fused dinv = rsqrt(deg+1)
// ---------------------------------------------------------------------------
__global__ __launch_bounds__(1024) void scan_kernel(const int* __restrict__ deg,
                                                    int* __restrict__ offsets,
                                                    float* __restrict__ dinv, int n) {
    __shared__ int part[1024];
    int t = threadIdx.x;
    int ch = (n + 1023) / 1024;
    int lo = t * ch, hi = min(lo + ch, n);
    int s = 0;
    for (int i = lo; i < hi; i++) {
        int dg = deg[i];
        s += dg;
        dinv[i] = rsqrtf((float)dg + 1.0f);
    }
    part[t] = s;
    __syncthreads();
    for (int off = 1; off < 1024; off <<= 1) {
        int v = (t >= off) ? part[t - off] : 0;
        __syncthreads();
        part[t] += v;
        __syncthreads();
    }
    int run = part[t] - s;
    if (t == 0) offsets[0] = 0;
    for (int i = lo; i < hi; i++) {
        run += deg[i];
        offsets[i + 1] = run;
    }
}

// ---------------------------------------------------------------------------
// 5. Scatter edges into CSR adjacency
// ---------------------------------------------------------------------------
__global__ void scatter_kernel(const int* __restrict__ ei, const int* __restrict__ offsets,
                               int* __restrict__ cursor, int* __restrict__ adj, int E) {
    int e = blockIdx.x * 256 + threadIdx.x;
    if (e < E) {
        int s = ei[e];
        int d = ei[E + e];
        int pos = offsets[d] + atomicAdd(&cursor[d], 1);
        adj[pos] = s;
    }
}

// ---------------------------------------------------------------------------
// 6. Cp8 += sum_{f, j<63} emb[f,j] * W1[f*64+j, k]  (8-way partial buffers)
// ---------------------------------------------------------------------------
__global__ __launch_bounds__(256) void cvec_kernel(const float* __restrict__ emb,
                                                   const float* __restrict__ W1,
                                                   float* __restrict__ Cp8) {
    __shared__ float4 red[8][32];
    int f = blockIdx.x;
    int t = threadIdx.x;
    int jg = t >> 5;
    int k4 = t & 31;
    float4 s = make_float4(0.f, 0.f, 0.f, 0.f);
    for (int j = jg; j < FEAT_EMB_; j += 8) {
        float e = emb[f * FEAT_EMB_ + j];
        float4 w = *(const float4*)(W1 + ((size_t)(f * 64 + j)) * HID_ + k4 * 4);
        s.x += e * w.x; s.y += e * w.y; s.z += e * w.z; s.w += e * w.w;
    }
    red[jg][k4] = s;
    __syncthreads();
    if (jg == 0) {
#pragma unroll
        for (int i = 1; i < 8; i++) {
            float4 a = red[i][k4];
            s.x += a.x; s.y += a.y; s.z += a.z; s.w += a.w;
        }
        int buf = (f & 7) * HID_;
        atomicAdd(&Cp8[buf + k4 * 4 + 0], s.x);
        atomicAdd(&Cp8[buf + k4 * 4 + 1], s.y);
        atomicAdd(&Cp8[buf + k4 * 4 + 2], s.z);
        atomicAdd(&Cp8[buf + k4 * 4 + 3], s.w);
    }
}

// ---------------------------------------------------------------------------
// 7. wprep: 8 blocks x 256 threads, each block owns 32 features.
//    Wfrag[kc][nt][lane][j] = bf16(rstd[f] * W1[f*64+63, n])  (B-frag linear:
//    element (k=f, n): kc=f>>5, j=f&7, lane=((f>>3)&3)*16+(n&15), nt=n>>4)
//    Cp contribution -mean[f]*w reduced block-locally -> 1 atomic/addr/block.
// ---------------------------------------------------------------------------
__global__ __launch_bounds__(256) void wprep_kernel(const float* __restrict__ W1,
                                                    const float* __restrict__ mean,
                                                    const float* __restrict__ rstd,
                                                    short* __restrict__ Wfrag,
                                                    float* __restrict__ Cp8) {
    __shared__ float red[256];
    int b = blockIdx.x;
    int t = threadIdx.x;
    int nn = t & 127;
    int fs = t >> 7;                 // 0/1
    float cacc = 0.f;
#pragma unroll
    for (int i = 0; i < 16; i++) {
        int f = b * 32 + i * 2 + fs;
        float w = W1[((size_t)(f * 64 + 63)) * HID_ + nn] * rstd[f];
        cacc -= mean[f] * w;
        int kc = f >> 5, j = f & 7, hi = (f >> 3) & 3;
        int lane = hi * 16 + (nn & 15);
        int nt = nn >> 4;
        Wfrag[(((kc * 8 + nt) * 64 + lane) << 3) + j] = f2bf(w);
    }
    red[t] = cacc;
    __syncthreads();
    if (t < 128) atomicAdd(&Cp8[b * HID_ + t], red[t] + red[t + 128]);
}

// ---------------------------------------------------------------------------
// 8. mm1: g0 = (Cp + x @ Wv) * dinv via MFMA 16x16x32 bf16. LDS-free K-loop:
//    A-frags straight from global x (lane reads its own 32B, wave covers the
//    16x32 tile exactly once, 128B/row coalescing), B-frags from the packed
//    L2-resident Wfrag. Block = 4 waves x 16 rows = 64 rows; 8 n-tiles.
// ---------------------------------------------------------------------------
__global__ __launch_bounds__(256) void mm1_kernel(const float* __restrict__ x,
                                                  const short* __restrict__ Wfrag,
                                                  const float* __restrict__ Cp8,
                                                  const float* __restrict__ dinv,
                                                  float* __restrict__ g0, int n) {
    __shared__ float cps[HID_];
    int t = threadIdx.x;
    if (t < HID_) {
        float s = 0.f;
#pragma unroll
        for (int b = 0; b < 8; b++) s += Cp8[b * HID_ + t];
        cps[t] = s;
    }
    __syncthreads();

    int wave = t >> 6, lane = t & 63;
    int m = lane & 15;
    int hi = lane >> 4;                    // 0..3
    int rowbase = blockIdx.x * 64 + wave * 16;
    int arow = rowbase + m;
    bool rok = arow < n;
    const float* xrow = x + (size_t)arow * F_ + hi * 8;

    f32x4 acc[8];
#pragma unroll
    for (int i = 0; i < 8; i++) acc[i] = (f32x4){0.f, 0.f, 0.f, 0.f};

#pragma unroll
    for (int kc = 0; kc < 8; kc++) {
        short8 af;
        if (rok) {
            float4 u0 = *(const float4*)(xrow + kc * 32);
            float4 u1 = *(const float4*)(xrow + kc * 32 + 4);
            af[0] = f2bf(u0.x); af[1] = f2bf(u0.y); af[2] = f2bf(u0.z); af[3] = f2bf(u0.w);
            af[4] = f2bf(u1.x); af[5] = f2bf(u1.y); af[6] = f2bf(u1.z); af[7] = f2bf(u1.w);
        } else {
            af = (short8){0, 0, 0, 0, 0, 0, 0, 0};
        }
#pragma unroll
        for (int nt = 0; nt < 8; nt++) {
            short8 bf = *(const short8*)(Wfrag + (((kc * 8 + nt) * 64 + lane) << 3));
            acc[nt] = __builtin_amdgcn_mfma_f32_16x16x32_bf16(af, bf, acc[nt], 0, 0, 0);
        }
    }

    // epilogue: C/D layout col=lane&15, row=(lane>>4)*4+reg
    float dv[4];
#pragma unroll
    for (int r = 0; r < 4; r++) {
        int gr = rowbase + hi * 4 + r;
        dv[r] = (gr < n) ? dinv[gr] : 0.f;
    }
#pragma unroll
    for (int nt = 0; nt < 8; nt++) {
        int col = nt * 16 + m;
        float cp = cps[col];
#pragma unroll
        for (int r = 0; r < 4; r++) {
            int gr = rowbase + hi * 4 + r;
            if (gr < n) g0[(size_t)gr * HID_ + col] = (acc[nt][r] + cp) * dv[r];
        }
    }
}

// ---------------------------------------------------------------------------
// 9. Layer-1 aggregation + ReLU + fused FC2.
// ---------------------------------------------------------------------------
__global__ __launch_bounds__(256) void agg_fc2_kernel(const float* __restrict__ g0,
                                                      const int* __restrict__ offsets,
                                                      const int* __restrict__ adj,
                                                      const float* __restrict__ dinv,
                                                      const float* __restrict__ b1,
                                                      const float* __restrict__ W2,
                                                      float* __restrict__ g2, int n) {
    int wave = threadIdx.x >> 6;
    int lane = threadIdx.x & 63;
    int d = blockIdx.x * 4 + wave;
    if (d >= n) return;

    int o0 = offsets[d];
    int o1 = offsets[d + 1];
    float2 acc = *(const float2*)(g0 + (size_t)d * HID_ + lane * 2);  // self loop

    for (int base = o0; base < o1; base += 64) {
        int idx = (base + lane < o1) ? adj[base + lane] : 0;
        int cnt = min(64, o1 - base);
        int j = 0;
        for (; j + 4 <= cnt; j += 4) {
            int s0 = __shfl(idx, j + 0);
            int s1 = __shfl(idx, j + 1);
            int s2 = __shfl(idx, j + 2);
            int s3 = __shfl(idx, j + 3);
            float2 v0 = *(const float2*)(g0 + (size_t)s0 * HID_ + lane * 2);
            float2 v1 = *(const float2*)(g0 + (size_t)s1 * HID_ + lane * 2);
            float2 v2 = *(const float2*)(g0 + (size_t)s2 * HID_ + lane * 2);
            float2 v3 = *(const float2*)(g0 + (size_t)s3 * HID_ + lane * 2);
            acc.x += v0.x + v1.x + v2.x + v3.x;
            acc.y += v0.y + v1.y + v2.y + v3.y;
        }
        for (; j < cnt; j++) {
            int s = __shfl(idx, j);
            float2 v = *(const float2*)(g0 + (size_t)s * HID_ + lane * 2);
            acc.x += v.x;
            acc.y += v.y;
        }
    }

    float dv = dinv[d];
    float2 bb = *(const float2*)(b1 + lane * 2);
    float h0 = fmaxf(acc.x * dv + bb.x, 0.f);
    float h1 = fmaxf(acc.y * dv + bb.y, 0.f);

    const float* w2a = W2 + (lane * 2) * OUT_;
    const float* w2b = W2 + (lane * 2 + 1) * OUT_;
    float r[OUT_];
#pragma unroll
    for (int c = 0; c < OUT_; c++) {
        float p = h0 * w2a[c] + h1 * w2b[c];
#pragma unroll
        for (int off = 32; off > 0; off >>= 1) p += __shfl_xor(p, off);
        r[c] = p;
    }
    if (lane < 8) {
        float val;
        switch (lane) {
            case 0: val = r[0]; break;
            case 1: val = r[1]; break;
            case 2: val = r[2]; break;
            case 3: val = r[3]; break;
            case 4: val = r[4]; break;
            case 5: val = r[5]; break;
            case 6: val = r[6]; break;
            default: val = 0.f; break;   // pad slot
        }
        g2[(size_t)d * 8 + lane] = val * dv;
    }
}

// ---------------------------------------------------------------------------
// 10. Layer-2 aggregation + bias + log_softmax. 8 lanes per node.
// ---------------------------------------------------------------------------
__global__ __launch_bounds__(256) void agg2_softmax_kernel(const float* __restrict__ g2,
                                                           const int* __restrict__ offsets,
                                                           const int* __restrict__ adj,
                                                           const float* __restrict__ dinv,
                                                           const float* __restrict__ b2,
                                                           float* __restrict__ out, int n) {
    int t = threadIdx.x;
    int g = t >> 3;
    int c = t & 7;
    int d = blockIdx.x * 32 + g;
    if (d >= n) return;

    int o0 = offsets[d];
    int o1 = offsets[d + 1];
    float acc = g2[(size_t)d * 8 + c];
    int i = o0;
    for (; i + 2 <= o1; i += 2) {
        int s0 = adj[i], s1 = adj[i + 1];
        acc += g2[(size_t)s0 * 8 + c] + g2[(size_t)s1 * 8 + c];
    }
    for (; i < o1; i++) acc += g2[(size_t)adj[i] * 8 + c];

    float z = (c < OUT_) ? (acc * dinv[d] + b2[c]) : -INFINITY;
    float m = z;
#pragma unroll
    for (int off = 4; off > 0; off >>= 1) m = fmaxf(m, __shfl_xor(m, off, 8));
    float e = (c < OUT_) ? __expf(z - m) : 0.f;
    float sum = e;
#pragma unroll
    for (int off = 4; off > 0; off >>= 1) sum += __shfl_xor(sum, off, 8);
    if (c < OUT_) out[(size_t)d * OUT_ + c] = z - m - __logf(sum);
}

// ---------------------------------------------------------------------------
// launch
// ---------------------------------------------------------------------------
extern "C" void kernel_launch(void* const* d_in, const int* in_sizes, int n_in,
                              void* d_out, int out_size, void* d_ws, size_t ws_size,
                              hipStream_t stream) {
    const float* x    = (const float*)d_in[0];
    const float* emb  = (const float*)d_in[1];
    const float* W1   = (const float*)d_in[2];
    const float* b1   = (const float*)d_in[3];
    const float* W2   = (const float*)d_in[4];
    const float* b2   = (const float*)d_in[5];
    const int*   ei   = (const int*)d_in[6];
    float* out = (float*)d_out;

    const int N = in_sizes[0] / F_;       // 20000
    const int E = in_sizes[6] / 2;        // 320000

    float* ws = (float*)d_ws;
    size_t o = 0;
    float* colsum8 = ws + o; o += 8 * F_;              // zeroed
    float* colsq8  = ws + o; o += 8 * F_;              // zeroed
    float* Cp8     = ws + o; o += 8 * HID_;            // zeroed
    size_t zero1_elems = o;                            // 5120 floats
    float* mean    = ws + o; o += F_;
    float* rstd    = ws + o; o += F_;
    short* Wfrag   = (short*)(ws + o); o += (size_t)F_ * HID_ / 2;  // 32768 bf16
    float* dinv    = ws + o; o += N;
    int*   deg     = (int*)(ws + o); o += N;
    int*   cursor  = (int*)(ws + o); o += N;           // contiguous with deg
    int*   offsets = (int*)(ws + o); o += (size_t)N + 1;
    o = (o + 3) & ~(size_t)3;
    int*   adj     = (int*)(ws + o); o += E;
    o = (o + 3) & ~(size_t)3;
    float* g0      = ws + o; o += (size_t)N * HID_;
    float* g2      = ws + o; o += (size_t)N * 8;

    hipMemsetAsync(ws, 0, zero1_elems * sizeof(float), stream);
    hipMemsetAsync(deg, 0, (size_t)2 * N * sizeof(int), stream);

    colstats_kernel<<<N / 32, 256, 0, stream>>>(x, colsum8, colsq8);
    deg_kernel<<<(E + 255) / 256, 256, 0, stream>>>(ei, deg, E);
    cvec_kernel<<<F_, 256, 0, stream>>>(emb, W1, Cp8);
    stats_kernel<<<1, 256, 0, stream>>>(colsum8, colsq8, mean, rstd, N);
    scan_kernel<<<1, 1024, 0, stream>>>(deg, offsets, dinv, N);
    scatter_kernel<<<(E + 255) / 256, 256, 0, stream>>>(ei, offsets, cursor, adj, E);
    wprep_kernel<<<8, 256, 0, stream>>>(W1, mean, rstd, Wfrag, Cp8);
    mm1_kernel<<<(N + 63) / 64, 256, 0, stream>>>(x, Wfrag, Cp8, dinv, g0, N);
    agg_fc2_kernel<<<(N + 3) / 4, 256, 0, stream>>>(g0, offsets, adj, dinv, b1, W2, g2, N);
    agg2_softmax_kernel<<<(N + 31) / 32, 256, 0, stream>>>(g2, offsets, adj, dinv, b2, out, N);
}

// Round 5
// 209.638 us; speedup vs baseline: 1.4907x; 1.0759x over previous
//
#include <hip/hip_runtime.h>
#include <math.h>

#define F_   256
#define FEAT_EMB_ 63
#define HID_ 128
#define OUT_ 7

typedef short short8 __attribute__((ext_vector_type(8)));
typedef float f32x4 __attribute__((ext_vector_type(4)));

__device__ inline short f2bf(float f) {
    unsigned u = __float_as_uint(f);
    u += 0x7FFFu + ((u >> 16) & 1u);     // round-to-nearest-even
    return (short)(u >> 16);
}

// ===========================================================================
// FRONT: three independent jobs fused by block range (saves 2 dispatches and
// overlaps three latency-bound kernels):
//   blocks [0,625)        colstats  (8-way partial buffers, R4 win)
//   blocks [625,1875)     deg histogram
//   blocks [1875,2131)    cvec (Cp8 partial buffers)
// ===========================================================================
#define FRONT_CS  625
#define FRONT_DEG 1250
#define FRONT_CV  256

__global__ __launch_bounds__(256) void front_kernel(const float* __restrict__ x,
                                                    const int* __restrict__ ei,
                                                    const float* __restrict__ emb,
                                                    const float* __restrict__ W1,
                                                    float* __restrict__ colsum8,
                                                    float* __restrict__ colsq8,
                                                    int* __restrict__ deg,
                                                    float* __restrict__ Cp8, int E) {
    __shared__ float4 smem[8][64];       // shared by both LDS users
    int b = blockIdx.x;
    int t = threadIdx.x;

    if (b < FRONT_CS) {
        // ---- colstats: 32 rows per block, N = 625*32 exactly ----
        int rl = t >> 6;
        int lane = t & 63;
        int row0 = b * 32 + rl * 8;
        float4 v[8];
#pragma unroll
        for (int i = 0; i < 8; i++)
            v[i] = *(const float4*)(x + (size_t)(row0 + i) * F_ + lane * 4);
        float4 s = make_float4(0.f, 0.f, 0.f, 0.f);
        float4 q = make_float4(0.f, 0.f, 0.f, 0.f);
#pragma unroll
        for (int i = 0; i < 8; i++) {
            s.x += v[i].x; s.y += v[i].y; s.z += v[i].z; s.w += v[i].w;
            q.x += v[i].x * v[i].x; q.y += v[i].y * v[i].y;
            q.z += v[i].z * v[i].z; q.w += v[i].w * v[i].w;
        }
        smem[rl][lane] = s;
        smem[rl + 4][lane] = q;
        __syncthreads();
        if (rl == 0) {
#pragma unroll
            for (int i = 1; i < 4; i++) {
                float4 a = smem[i][lane], bb = smem[i + 4][lane];
                s.x += a.x; s.y += a.y; s.z += a.z; s.w += a.w;
                q.x += bb.x; q.y += bb.y; q.z += bb.z; q.w += bb.w;
            }
            int buf = (b & 7) * F_;
            atomicAdd(&colsum8[buf + lane * 4 + 0], s.x);
            atomicAdd(&colsum8[buf + lane * 4 + 1], s.y);
            atomicAdd(&colsum8[buf + lane * 4 + 2], s.z);
            atomicAdd(&colsum8[buf + lane * 4 + 3], s.w);
            atomicAdd(&colsq8[buf + lane * 4 + 0], q.x);
            atomicAdd(&colsq8[buf + lane * 4 + 1], q.y);
            atomicAdd(&colsq8[buf + lane * 4 + 2], q.z);
            atomicAdd(&colsq8[buf + lane * 4 + 3], q.w);
        }
    } else if (b < FRONT_CS + FRONT_DEG) {
        // ---- deg histogram (dst side) ----
        int e = (b - FRONT_CS) * 256 + t;
        if (e < E) atomicAdd(&deg[ei[E + e]], 1);
    } else {
        // ---- cvec: Cp8 += sum_{j<63} emb[f,j] * W1[f*64+j, :] ----
        int f = b - (FRONT_CS + FRONT_DEG);
        int jg = t >> 5;
        int k4 = t & 31;
        float4 s = make_float4(0.f, 0.f, 0.f, 0.f);
        for (int j = jg; j < FEAT_EMB_; j += 8) {
            float e = emb[f * FEAT_EMB_ + j];
            float4 w = *(const float4*)(W1 + ((size_t)(f * 64 + j)) * HID_ + k4 * 4);
            s.x += e * w.x; s.y += e * w.y; s.z += e * w.z; s.w += e * w.w;
        }
        smem[jg][k4] = s;
        __syncthreads();
        if (jg == 0) {
#pragma unroll
            for (int i = 1; i < 8; i++) {
                float4 a = smem[i][k4];
                s.x += a.x; s.y += a.y; s.z += a.z; s.w += a.w;
            }
            int buf = (f & 7) * HID_;
            atomicAdd(&Cp8[buf + k4 * 4 + 0], s.x);
            atomicAdd(&Cp8[buf + k4 * 4 + 1], s.y);
            atomicAdd(&Cp8[buf + k4 * 4 + 2], s.z);
            atomicAdd(&Cp8[buf + k4 * 4 + 3], s.w);
        }
    }
}

// ===========================================================================
// MID: block 0 = CSR scan (+dinv); blocks 1..8 = wprep (stats inline from the
// 8 partial buffers, so no separate stats dispatch).
//   Wfrag B-frag-linear layout: element (k=f, n): kc=f>>5, j=f&7,
//   lane=((f>>3)&3)*16+(n&15), nt=n>>4.
// ===========================================================================
__global__ __launch_bounds__(1024) void mid_kernel(const int* __restrict__ deg,
                                                   int* __restrict__ offsets,
                                                   float* __restrict__ dinv,
                                                   const float* __restrict__ colsum8,
                                                   const float* __restrict__ colsq8,
                                                   const float* __restrict__ W1,
                                                   short* __restrict__ Wfrag,
                                                   float* __restrict__ Cp8, int n) {
    int t = threadIdx.x;
    if (blockIdx.x == 0) {
        // ---- exclusive scan + dinv ----
        __shared__ int part[1024];
        int ch = (n + 1023) / 1024;
        int lo = t * ch, hi = min(lo + ch, n);
        int s = 0;
        for (int i = lo; i < hi; i++) {
            int dg = deg[i];
            s += dg;
            dinv[i] = rsqrtf((float)dg + 1.0f);
        }
        part[t] = s;
        __syncthreads();
        for (int off = 1; off < 1024; off <<= 1) {
            int v = (t >= off) ? part[t - off] : 0;
            __syncthreads();
            part[t] += v;
            __syncthreads();
        }
        int run = part[t] - s;
        if (t == 0) offsets[0] = 0;
        for (int i = lo; i < hi; i++) {
            run += deg[i];
            offsets[i + 1] = run;
        }
    } else {
        // ---- wprep: 32 features per block ----
        __shared__ float red[256];
        __shared__ float sm[32], sr[32];
        int b = blockIdx.x - 1;
        if (t < 32) {                          // per-feature stats from partials
            int f = b * 32 + t;
            float s = 0.f, q = 0.f;
#pragma unroll
            for (int p = 0; p < 8; p++) {
                s += colsum8[p * F_ + f];
                q += colsq8[p * F_ + f];
            }
            float m = s / (float)n;
            float var = fmaxf(q / (float)n - m * m, 0.f);
            float sd = sqrtf(var);
            sm[t] = m;
            sr[t] = (sd == 0.f) ? 1.f : (1.f / sd);
        }
        __syncthreads();
        if (t < 256) {
            int nn = t & 127;
            int fs = t >> 7;                   // 0/1
            float cacc = 0.f;
#pragma unroll
            for (int i = 0; i < 16; i++) {
                int fl = i * 2 + fs;
                int f = b * 32 + fl;
                float w = W1[((size_t)(f * 64 + 63)) * HID_ + nn] * sr[fl];
                cacc -= sm[fl] * w;
                int kc = f >> 5, j = f & 7, hi2 = (f >> 3) & 3;
                int lane = hi2 * 16 + (nn & 15);
                int nt = nn >> 4;
                Wfrag[(((kc * 8 + nt) * 64 + lane) << 3) + j] = f2bf(w);
            }
            red[t] = cacc;
        }
        __syncthreads();
        if (t < 128) atomicAdd(&Cp8[b * HID_ + t], red[t] + red[t + 128]);
    }
}

// ===========================================================================
// WORK: blocks [0,1250) = CSR scatter; blocks [1250,1563) = mm1 (MFMA bf16,
// LDS-free K-loop, g0 written as packed bf16 -> halves agg_fc2 gather volume).
// ===========================================================================
#define WORK_SC 1250

__global__ __launch_bounds__(256) void work_kernel(const int* __restrict__ ei,
                                                   const int* __restrict__ offsets,
                                                   int* __restrict__ cursor,
                                                   int* __restrict__ adj,
                                                   const float* __restrict__ x,
                                                   const short* __restrict__ Wfrag,
                                                   const float* __restrict__ Cp8,
                                                   const float* __restrict__ dinv,
                                                   unsigned short* __restrict__ g0b,
                                                   int E, int n) {
    int t = threadIdx.x;
    if (blockIdx.x < WORK_SC) {
        // ---- scatter edges into CSR ----
        int e = blockIdx.x * 256 + t;
        if (e < E) {
            int s = ei[e];
            int d = ei[E + e];
            int pos = offsets[d] + atomicAdd(&cursor[d], 1);
            adj[pos] = s;
        }
        return;
    }
    // ---- mm1 ----
    __shared__ float cps[HID_];
    if (t < HID_) {
        float s = 0.f;
#pragma unroll
        for (int b = 0; b < 8; b++) s += Cp8[b * HID_ + t];
        cps[t] = s;
    }
    __syncthreads();

    int wave = t >> 6, lane = t & 63;
    int m = lane & 15;
    int hi = lane >> 4;
    int rowbase = (blockIdx.x - WORK_SC) * 64 + wave * 16;
    int arow = rowbase + m;
    bool rok = arow < n;
    const float* xrow = x + (size_t)arow * F_ + hi * 8;

    f32x4 acc[8];
#pragma unroll
    for (int i = 0; i < 8; i++) acc[i] = (f32x4){0.f, 0.f, 0.f, 0.f};

#pragma unroll
    for (int kc = 0; kc < 8; kc++) {
        short8 af;
        if (rok) {
            float4 u0 = *(const float4*)(xrow + kc * 32);
            float4 u1 = *(const float4*)(xrow + kc * 32 + 4);
            af[0] = f2bf(u0.x); af[1] = f2bf(u0.y); af[2] = f2bf(u0.z); af[3] = f2bf(u0.w);
            af[4] = f2bf(u1.x); af[5] = f2bf(u1.y); af[6] = f2bf(u1.z); af[7] = f2bf(u1.w);
        } else {
            af = (short8){0, 0, 0, 0, 0, 0, 0, 0};
        }
#pragma unroll
        for (int nt = 0; nt < 8; nt++) {
            short8 bf = *(const short8*)(Wfrag + (((kc * 8 + nt) * 64 + lane) << 3));
            acc[nt] = __builtin_amdgcn_mfma_f32_16x16x32_bf16(af, bf, acc[nt], 0, 0, 0);
        }
    }

    float dv[4];
#pragma unroll
    for (int r = 0; r < 4; r++) {
        int gr = rowbase + hi * 4 + r;
        dv[r] = (gr < n) ? dinv[gr] : 0.f;
    }
#pragma unroll
    for (int nt = 0; nt < 8; nt++) {
        int col = nt * 16 + m;
        float cp = cps[col];
#pragma unroll
        for (int r = 0; r < 4; r++) {
            int gr = rowbase + hi * 4 + r;
            if (gr < n) g0b[(size_t)gr * HID_ + col] = (unsigned short)f2bf((acc[nt][r] + cp) * dv[r]);
        }
    }
}

// ===========================================================================
// Layer-1 aggregation (bf16 g0 gather) + ReLU + fused FC2
// ===========================================================================
__global__ __launch_bounds__(256) void agg_fc2_kernel(const unsigned short* __restrict__ g0b,
                                                      const int* __restrict__ offsets,
                                                      const int* __restrict__ adj,
                                                      const float* __restrict__ dinv,
                                                      const float* __restrict__ b1,
                                                      const float* __restrict__ W2,
                                                      float* __restrict__ g2, int n) {
    int wave = threadIdx.x >> 6;
    int lane = threadIdx.x & 63;
    int d = blockIdx.x * 4 + wave;
    if (d >= n) return;

    int o0 = offsets[d];
    int o1 = offsets[d + 1];
    unsigned u = *(const unsigned*)(g0b + (size_t)d * HID_ + lane * 2);  // self
    float ax = __uint_as_float(u << 16);
    float ay = __uint_as_float(u & 0xFFFF0000u);

    for (int base = o0; base < o1; base += 64) {
        int idx = (base + lane < o1) ? adj[base + lane] : 0;
        int cnt = min(64, o1 - base);
        int j = 0;
        for (; j + 4 <= cnt; j += 4) {
            int s0 = __shfl(idx, j + 0);
            int s1 = __shfl(idx, j + 1);
            int s2 = __shfl(idx, j + 2);
            int s3 = __shfl(idx, j + 3);
            unsigned u0 = *(const unsigned*)(g0b + (size_t)s0 * HID_ + lane * 2);
            unsigned u1 = *(const unsigned*)(g0b + (size_t)s1 * HID_ + lane * 2);
            unsigned u2 = *(const unsigned*)(g0b + (size_t)s2 * HID_ + lane * 2);
            unsigned u3 = *(const unsigned*)(g0b + (size_t)s3 * HID_ + lane * 2);
            ax += __uint_as_float(u0 << 16) + __uint_as_float(u1 << 16)
                + __uint_as_float(u2 << 16) + __uint_as_float(u3 << 16);
            ay += __uint_as_float(u0 & 0xFFFF0000u) + __uint_as_float(u1 & 0xFFFF0000u)
                + __uint_as_float(u2 & 0xFFFF0000u) + __uint_as_float(u3 & 0xFFFF0000u);
        }
        for (; j < cnt; j++) {
            int s = __shfl(idx, j);
            unsigned uu = *(const unsigned*)(g0b + (size_t)s * HID_ + lane * 2);
            ax += __uint_as_float(uu << 16);
            ay += __uint_as_float(uu & 0xFFFF0000u);
        }
    }

    float dv = dinv[d];
    float2 bb = *(const float2*)(b1 + lane * 2);
    float h0 = fmaxf(ax * dv + bb.x, 0.f);
    float h1 = fmaxf(ay * dv + bb.y, 0.f);

    const float* w2a = W2 + (lane * 2) * OUT_;
    const float* w2b = W2 + (lane * 2 + 1) * OUT_;
    float r[OUT_];
#pragma unroll
    for (int c = 0; c < OUT_; c++) {
        float p = h0 * w2a[c] + h1 * w2b[c];
#pragma unroll
        for (int off = 32; off > 0; off >>= 1) p += __shfl_xor(p, off);
        r[c] = p;
    }
    if (lane < 8) {
        float val;
        switch (lane) {
            case 0: val = r[0]; break;
            case 1: val = r[1]; break;
            case 2: val = r[2]; break;
            case 3: val = r[3]; break;
            case 4: val = r[4]; break;
            case 5: val = r[5]; break;
            case 6: val = r[6]; break;
            default: val = 0.f; break;
        }
        g2[(size_t)d * 8 + lane] = val * dv;
    }
}

// ===========================================================================
// Layer-2 aggregation + bias + log_softmax. 8 lanes per node.
// ===========================================================================
__global__ __launch_bounds__(256) void agg2_softmax_kernel(const float* __restrict__ g2,
                                                           const int* __restrict__ offsets,
                                                           const int* __restrict__ adj,
                                                           const float* __restrict__ dinv,
                                                           const float* __restrict__ b2,
                                                           float* __restrict__ out, int n) {
    int t = threadIdx.x;
    int g = t >> 3;
    int c = t & 7;
    int d = blockIdx.x * 32 + g;
    if (d >= n) return;

    int o0 = offsets[d];
    int o1 = offsets[d + 1];
    float acc = g2[(size_t)d * 8 + c];
    int i = o0;
    for (; i + 2 <= o1; i += 2) {
        int s0 = adj[i], s1 = adj[i + 1];
        acc += g2[(size_t)s0 * 8 + c] + g2[(size_t)s1 * 8 + c];
    }
    for (; i < o1; i++) acc += g2[(size_t)adj[i] * 8 + c];

    float z = (c < OUT_) ? (acc * dinv[d] + b2[c]) : -INFINITY;
    float m = z;
#pragma unroll
    for (int off = 4; off > 0; off >>= 1) m = fmaxf(m, __shfl_xor(m, off, 8));
    float e = (c < OUT_) ? __expf(z - m) : 0.f;
    float sum = e;
#pragma unroll
    for (int off = 4; off > 0; off >>= 1) sum += __shfl_xor(sum, off, 8);
    if (c < OUT_) out[(size_t)d * OUT_ + c] = z - m - __logf(sum);
}

// ---------------------------------------------------------------------------
// launch
// ---------------------------------------------------------------------------
extern "C" void kernel_launch(void* const* d_in, const int* in_sizes, int n_in,
                              void* d_out, int out_size, void* d_ws, size_t ws_size,
                              hipStream_t stream) {
    const float* x    = (const float*)d_in[0];
    const float* emb  = (const float*)d_in[1];
    const float* W1   = (const float*)d_in[2];
    const float* b1   = (const float*)d_in[3];
    const float* W2   = (const float*)d_in[4];
    const float* b2   = (const float*)d_in[5];
    const int*   ei   = (const int*)d_in[6];
    float* out = (float*)d_out;

    const int N = in_sizes[0] / F_;       // 20000
    const int E = in_sizes[6] / 2;        // 320000

    float* ws = (float*)d_ws;
    size_t o = 0;
    float* colsum8 = ws + o; o += 8 * F_;              // zeroed
    float* colsq8  = ws + o; o += 8 * F_;              // zeroed
    float* Cp8     = ws + o; o += 8 * HID_;            // zeroed
    size_t zero1_elems = o;                            // 5120 floats
    short* Wfrag   = (short*)(ws + o); o += (size_t)F_ * HID_ / 2;  // 32768 bf16
    float* dinv    = ws + o; o += N;
    int*   deg     = (int*)(ws + o); o += N;
    int*   cursor  = (int*)(ws + o); o += N;           // contiguous with deg
    int*   offsets = (int*)(ws + o); o += (size_t)N + 1;
    o = (o + 3) & ~(size_t)3;
    int*   adj     = (int*)(ws + o); o += E;
    o = (o + 3) & ~(size_t)3;
    unsigned short* g0b = (unsigned short*)(ws + o); o += (size_t)N * HID_ / 2;
    float* g2      = ws + o; o += (size_t)N * 8;

    hipMemsetAsync(ws, 0, zero1_elems * sizeof(float), stream);
    hipMemsetAsync(deg, 0, (size_t)2 * N * sizeof(int), stream);

    front_kernel<<<FRONT_CS + FRONT_DEG + FRONT_CV, 256, 0, stream>>>(
        x, ei, emb, W1, colsum8, colsq8, deg, Cp8, E);
    mid_kernel<<<9, 1024, 0, stream>>>(deg, offsets, dinv, colsum8, colsq8, W1, Wfrag, Cp8, N);
    work_kernel<<<WORK_SC + (N + 63) / 64, 256, 0, stream>>>(
        ei, offsets, cursor, adj, x, Wfrag, Cp8, dinv, g0b, E, N);
    agg_fc2_kernel<<<(N + 3) / 4, 256, 0, stream>>>(g0b, offsets, adj, dinv, b1, W2, g2, N);
    agg2_softmax_kernel<<<(N + 31) / 32, 256, 0, stream>>>(g2, offsets, adj, dinv, b2, out, N);
}